// Round 1
// 535.429 us; speedup vs baseline: 1.1805x; 1.1805x over previous
//
#include <hip/hip_runtime.h>
#include <stdint.h>

#define SEQ 4096
#define DIM 1024

typedef __bf16 bf16x8 __attribute__((ext_vector_type(8)));
typedef float f32x4 __attribute__((ext_vector_type(4)));
typedef unsigned short u16;

__device__ __forceinline__ u16 f2bf(float f) {
    unsigned u = __float_as_uint(f);
    u += 0x7fffu + ((u >> 16) & 1u);     // RNE
    return (u16)(u >> 16);
}
__device__ __forceinline__ float bf2f(u16 h) {
    return __uint_as_float(((unsigned)h) << 16);
}

// global(16B) -> LDS direct copy; LDS dest is wave-uniform base + lane*16.
__device__ __forceinline__ void gload16(const u16* g, u16* l) {
    __builtin_amdgcn_global_load_lds(
        (const __attribute__((address_space(1))) void*)g,
        (__attribute__((address_space(3))) void*)l, 16, 0, 0);
}

// ---------------------------------------------------------------------------
// Kernel 1: h = rmsnorm(emb[x]) * norm_w, written directly as bf16 hi/lo pair
// ---------------------------------------------------------------------------
__global__ __launch_bounds__(256) void embed_rmsnorm_split(
    const int* __restrict__ x, const float* __restrict__ emb,
    const float* __restrict__ nw, u16* __restrict__ hh, u16* __restrict__ hl)
{
    const int row  = blockIdx.x;
    const int t    = threadIdx.x;
    const int lane = t & 63, wave = t >> 6;

    bool i64 = true;
    #pragma unroll
    for (int i = 1; i < 128; i += 2) i64 = i64 && (x[i] == 0);
    const int id = i64 ? x[2 * row] : x[row];

    float4 e = *(const float4*)(emb + (size_t)id * DIM + t * 4);
    float ss = e.x*e.x + e.y*e.y + e.z*e.z + e.w*e.w;
    #pragma unroll
    for (int off = 32; off > 0; off >>= 1) ss += __shfl_down(ss, off);

    __shared__ float red[4];
    if (lane == 0) red[wave] = ss;
    __syncthreads();
    float sum = red[0] + red[1] + red[2] + red[3];
    float scale = rsqrtf(sum * (1.0f / DIM) + 1.1920929e-7f);  // fp32 eps

    float4 n = *(const float4*)(nw + t * 4);
    float o0 = e.x * scale * n.x;
    float o1 = e.y * scale * n.y;
    float o2 = e.z * scale * n.z;
    float o3 = e.w * scale * n.w;
    ushort4 oh, ol;
    u16 b;
    b = f2bf(o0); oh.x = b; ol.x = f2bf(o0 - bf2f(b));
    b = f2bf(o1); oh.y = b; ol.y = f2bf(o1 - bf2f(b));
    b = f2bf(o2); oh.z = b; ol.z = f2bf(o2 - bf2f(b));
    b = f2bf(o3); oh.w = b; ol.w = f2bf(o3 - bf2f(b));
    *(ushort4*)(hh + (size_t)row * DIM + t * 4) = oh;
    *(ushort4*)(hl + (size_t)row * DIM + t * 4) = ol;
}

// ---------------------------------------------------------------------------
// Kernel 1b: split Wq/Wk/Wv fp32 -> bf16 hi/lo (once, outside all GEMM loops)
// grid: (DIM*DIM/1024, 3); 4 elems/thread
// ---------------------------------------------------------------------------
__global__ __launch_bounds__(256) void split_w(
    const float* __restrict__ W0, const float* __restrict__ W1,
    const float* __restrict__ W2, u16* __restrict__ H, u16* __restrict__ L)
{
    const float* W = (blockIdx.y == 0) ? W0 : (blockIdx.y == 1) ? W1 : W2;
    const size_t base = (size_t)blockIdx.y * DIM * DIM;
    const int i = (blockIdx.x * 256 + threadIdx.x) * 4;
    float4 w = *(const float4*)(W + i);
    ushort4 h, l;
    u16 b;
    b = f2bf(w.x); h.x = b; l.x = f2bf(w.x - bf2f(b));
    b = f2bf(w.y); h.y = b; l.y = f2bf(w.y - bf2f(b));
    b = f2bf(w.z); h.z = b; l.z = f2bf(w.z - bf2f(b));
    b = f2bf(w.w); h.w = b; l.w = f2bf(w.w - bf2f(b));
    *(ushort4*)(H + base + i) = h;
    *(ushort4*)(L + base + i) = l;
}

// ---------------------------------------------------------------------------
// Kernel 2: 3-pass split-precision GEMM on PRE-SPLIT bf16 hi/lo operands.
// C[M,N] = (Ah+Al)[M,K] * (Bh+Bl)[N,K]^T, acc = AhBh + AhBl + AlBh.
// 128x128 tile, BK=32, 4 waves, 4x4 MFMAs/wave, global_load_lds staging
// (m97 structure). Zero in-loop conversion VALU.
// OUT_MODE 0: fp32 C0.  1: bf16 split pair C0=hi, C1=lo.  2: bf16 C0, C^T.
// ---------------------------------------------------------------------------
template<int OUT_MODE>
__global__ __launch_bounds__(256, 2) void gemm_split3(
    const u16* __restrict__ Ah, const u16* __restrict__ Al, int lda,
    const u16* __restrict__ Bh, const u16* __restrict__ Bl, int ldb,
    void* __restrict__ C0, void* __restrict__ C1, int ldc, int K)
{
    __shared__ __align__(16) u16 Ash[128 * 32];
    __shared__ __align__(16) u16 Asl[128 * 32];
    __shared__ __align__(16) u16 Bsh[128 * 32];
    __shared__ __align__(16) u16 Bsl[128 * 32];

    const int tid  = threadIdx.x;
    const int lane = tid & 63;
    const int wave = tid >> 6;
    const int m0   = blockIdx.y * 128;
    const int n0   = blockIdx.x * 128;
    const int wr   = (wave >> 1) * 64;
    const int wc   = (wave & 1) * 64;
    const int half = lane >> 4;
    const int l16  = lane & 15;

    f32x4 acc[4][4] = {};

    const int arow = tid >> 2;          // row within 64-row half
    const int acol = (tid & 3) * 8;     // 8 consecutive k per thread
    const int wb   = wave * 512;        // wave's 1KB LDS chunk (u16 index)

    for (int k0 = 0; k0 < K; k0 += 32) {
        __syncthreads();   // prior iteration's LDS reads complete
        const size_t aoff = (size_t)(m0 + arow) * lda + k0 + acol;
        const size_t boff = (size_t)(n0 + arow) * ldb + k0 + acol;
        gload16(Ah + aoff,                    &Ash[wb]);
        gload16(Ah + aoff + (size_t)64 * lda, &Ash[2048 + wb]);
        gload16(Al + aoff,                    &Asl[wb]);
        gload16(Al + aoff + (size_t)64 * lda, &Asl[2048 + wb]);
        gload16(Bh + boff,                    &Bsh[wb]);
        gload16(Bh + boff + (size_t)64 * ldb, &Bsh[2048 + wb]);
        gload16(Bl + boff,                    &Bsl[wb]);
        gload16(Bl + boff + (size_t)64 * ldb, &Bsl[2048 + wb]);
        __syncthreads();   // compiler emits vmcnt(0) drain -> tile ready

        bf16x8 afh[4], afl[4], bfh[4], bfl[4];
        #pragma unroll
        for (int i = 0; i < 4; ++i) {
            afh[i] = *(const bf16x8*)&Ash[(wr + i*16 + l16) * 32 + half * 8];
            afl[i] = *(const bf16x8*)&Asl[(wr + i*16 + l16) * 32 + half * 8];
        }
        #pragma unroll
        for (int j = 0; j < 4; ++j) {
            bfh[j] = *(const bf16x8*)&Bsh[(wc + j*16 + l16) * 32 + half * 8];
            bfl[j] = *(const bf16x8*)&Bsl[(wc + j*16 + l16) * 32 + half * 8];
        }
        #pragma unroll
        for (int i = 0; i < 4; ++i)
            #pragma unroll
            for (int j = 0; j < 4; ++j) {
                acc[i][j] = __builtin_amdgcn_mfma_f32_16x16x32_bf16(afh[i], bfh[j], acc[i][j], 0, 0, 0);
                acc[i][j] = __builtin_amdgcn_mfma_f32_16x16x32_bf16(afh[i], bfl[j], acc[i][j], 0, 0, 0);
                acc[i][j] = __builtin_amdgcn_mfma_f32_16x16x32_bf16(afl[i], bfh[j], acc[i][j], 0, 0, 0);
            }
    }

    // C/D layout: col = lane&15, row = (lane>>4)*4 + reg   [m89/m91 verified]
    #pragma unroll
    for (int i = 0; i < 4; ++i)
        #pragma unroll
        for (int j = 0; j < 4; ++j)
            #pragma unroll
            for (int r = 0; r < 4; ++r) {
                int row = m0 + wr + i * 16 + half * 4 + r;
                int col = n0 + wc + j * 16 + l16;
                float val = acc[i][j][r];
                if constexpr (OUT_MODE == 0) {
                    ((float*)C0)[(size_t)row * ldc + col] = val;
                } else if constexpr (OUT_MODE == 1) {
                    u16 hi = f2bf(val);
                    ((u16*)C0)[(size_t)row * ldc + col] = hi;
                    ((u16*)C1)[(size_t)row * ldc + col] = f2bf(val - bf2f(hi));
                } else {
                    ((u16*)C0)[(size_t)col * ldc + row] = f2bf(val);
                }
            }
}

// ---------------------------------------------------------------------------
// Kernel 3: plain bf16 MFMA GEMM C = A*B^T, fused silu, fp32 out, gload_lds
// staging. A: bf16 [M,K] element pitch lda (packed P view); B: bf16 [N,K].
// ---------------------------------------------------------------------------
__global__ __launch_bounds__(256, 2) void gemm_bt_silu(
    const u16* __restrict__ A, int lda,
    const u16* __restrict__ B, int ldb,
    float* __restrict__ C, int ldc, int K)
{
    __shared__ __align__(16) u16 As[128 * 32];
    __shared__ __align__(16) u16 Bs[128 * 32];

    const int tid  = threadIdx.x;
    const int lane = tid & 63;
    const int wave = tid >> 6;
    const int m0   = blockIdx.y * 128;
    const int n0   = blockIdx.x * 128;
    const int wr   = (wave >> 1) * 64;
    const int wc   = (wave & 1) * 64;
    const int half = lane >> 4;
    const int l16  = lane & 15;

    f32x4 acc[4][4] = {};
    const int arow = tid >> 2;
    const int acol = (tid & 3) * 8;
    const int wb   = wave * 512;

    for (int k0 = 0; k0 < K; k0 += 32) {
        __syncthreads();
        gload16(A + (size_t)(m0 + arow)      * lda + k0 + acol, &As[wb]);
        gload16(A + (size_t)(m0 + 64 + arow) * lda + k0 + acol, &As[2048 + wb]);
        gload16(B + (size_t)(n0 + arow)      * ldb + k0 + acol, &Bs[wb]);
        gload16(B + (size_t)(n0 + 64 + arow) * ldb + k0 + acol, &Bs[2048 + wb]);
        __syncthreads();

        bf16x8 af[4], bfr[4];
        #pragma unroll
        for (int i = 0; i < 4; ++i)
            af[i] = *(const bf16x8*)&As[(wr + i*16 + l16) * 32 + half * 8];
        #pragma unroll
        for (int j = 0; j < 4; ++j)
            bfr[j] = *(const bf16x8*)&Bs[(wc + j*16 + l16) * 32 + half * 8];
        #pragma unroll
        for (int i = 0; i < 4; ++i)
            #pragma unroll
            for (int j = 0; j < 4; ++j)
                acc[i][j] = __builtin_amdgcn_mfma_f32_16x16x32_bf16(af[i], bfr[j], acc[i][j], 0, 0, 0);
    }

    #pragma unroll
    for (int i = 0; i < 4; ++i)
        #pragma unroll
        for (int j = 0; j < 4; ++j)
            #pragma unroll
            for (int r = 0; r < 4; ++r) {
                int row = m0 + wr + i * 16 + half * 4 + r;
                int col = n0 + wc + j * 16 + l16;
                float v = acc[i][j][r];
                v = v / (1.0f + __expf(-v));   // silu
                C[(size_t)row * ldc + col] = v;
            }
}

// ---------------------------------------------------------------------------
// Kernel 4: row softmax over fp32 [SEQ, SEQ]; writes bf16 P packed in-place
// into each row's own fp32 footprint (element pitch 2*SEQ u16 per row).
// ---------------------------------------------------------------------------
__global__ __launch_bounds__(256) void softmax_rows(float* __restrict__ S)
{
    const int row  = blockIdx.x;
    const int t    = threadIdx.x;
    const int lane = t & 63, wave = t >> 6;
    float* rp = S + (size_t)row * SEQ;

    float v[16];
    #pragma unroll
    for (int i = 0; i < 4; ++i) {
        float4 f = *(const float4*)(rp + i * 1024 + t * 4);
        v[i*4+0] = f.x; v[i*4+1] = f.y; v[i*4+2] = f.z; v[i*4+3] = f.w;
    }

    float m = v[0];
    #pragma unroll
    for (int i = 1; i < 16; ++i) m = fmaxf(m, v[i]);
    #pragma unroll
    for (int off = 32; off > 0; off >>= 1) m = fmaxf(m, __shfl_down(m, off));
    __shared__ float red[4];
    if (lane == 0) red[wave] = m;
    __syncthreads();
    m = fmaxf(fmaxf(red[0], red[1]), fmaxf(red[2], red[3]));
    __syncthreads();

    float s = 0.0f;
    #pragma unroll
    for (int i = 0; i < 16; ++i) { v[i] = __expf(v[i] - m); s += v[i]; }
    #pragma unroll
    for (int off = 32; off > 0; off >>= 1) s += __shfl_down(s, off);
    if (lane == 0) red[wave] = s;
    __syncthreads();
    s = red[0] + red[1] + red[2] + red[3];
    float inv = 1.0f / s;

    u16* op = (u16*)rp;
    #pragma unroll
    for (int i = 0; i < 4; ++i) {
        ushort4 o;
        o.x = f2bf(v[i*4+0] * inv);
        o.y = f2bf(v[i*4+1] * inv);
        o.z = f2bf(v[i*4+2] * inv);
        o.w = f2bf(v[i*4+3] * inv);
        *(ushort4*)(op + i * 1024 + t * 4) = o;
    }
}

// ---------------------------------------------------------------------------
extern "C" void kernel_launch(void* const* d_in, const int* in_sizes, int n_in,
                              void* d_out, int out_size, void* d_ws, size_t ws_size,
                              hipStream_t stream)
{
    // x int32; emb/norm_w/Wq/Wk/Wv fp32; OUTPUT fp32 (R7-proven contract)
    const int*   x   = (const int*)d_in[0];
    const float* emb = (const float*)d_in[1];
    const float* nw  = (const float*)d_in[2];
    const float* Wq  = (const float*)d_in[3];
    const float* Wk  = (const float*)d_in[4];
    const float* Wv  = (const float*)d_in[5];
    float* out = (float*)d_out;

    // ws layout (104 MB total, R7-proven size):
    //   [  0,  8) vT   bf16 [DIM,SEQ]
    //   [  8, 16) qh   bf16 [SEQ,DIM]
    //   [ 16, 24) ql
    //   [ 24, 32) kh
    //   [ 32, 40) kl
    //   [ 40,104) Sc   fp32 [SEQ,SEQ]
    //   hh/hl/Wh/Wl overlap the Sc head ([40,68)); they die after the QKV
    //   GEMMs, before the Sc GEMM writes (stream-ordered).
    char* ws = (char*)d_ws;
    u16*   vT = (u16*)(ws);
    u16*   qh = (u16*)(ws + ( 8u << 20));
    u16*   ql = (u16*)(ws + (16u << 20));
    u16*   kh = (u16*)(ws + (24u << 20));
    u16*   kl = (u16*)(ws + (32u << 20));
    float* Sc = (float*)(ws + (40u << 20));
    u16*   hh = (u16*)(ws + (40u << 20));
    u16*   hl = (u16*)(ws + (48u << 20));
    u16*   Wh = (u16*)(ws + (56u << 20));   // [3][DIM*DIM] = 6 MB
    u16*   Wl = (u16*)(ws + (62u << 20));   // [3][DIM*DIM] = 6 MB

    embed_rmsnorm_split<<<SEQ, 256, 0, stream>>>(x, emb, nw, hh, hl);
    split_w<<<dim3(DIM * DIM / 1024, 3), 256, 0, stream>>>(Wq, Wk, Wv, Wh, Wl);

    const size_t WSZ = (size_t)DIM * DIM;
    dim3 gqkv(DIM / 128, SEQ / 128);
    gemm_split3<1><<<gqkv, 256, 0, stream>>>(hh, hl, DIM, Wh,           Wl,           DIM, qh, ql,      DIM, DIM);
    gemm_split3<1><<<gqkv, 256, 0, stream>>>(hh, hl, DIM, Wh + WSZ,     Wl + WSZ,     DIM, kh, kl,      DIM, DIM);
    gemm_split3<2><<<gqkv, 256, 0, stream>>>(hh, hl, DIM, Wh + 2 * WSZ, Wl + 2 * WSZ, DIM, vT, nullptr, SEQ, DIM);

    dim3 gs(SEQ / 128, SEQ / 128);
    gemm_split3<0><<<gs, 256, 0, stream>>>(qh, ql, DIM, kh, kl, DIM, Sc, nullptr, SEQ, DIM);

    softmax_rows<<<SEQ, 256, 0, stream>>>(Sc);

    dim3 gpv(DIM / 128, SEQ / 128);
    // P viewed as bf16 with element pitch 8192; vT is B^T layout [DIM, SEQ]
    gemm_bt_silu<<<gpv, 256, 0, stream>>>((const u16*)Sc, 2 * SEQ, vT, SEQ, out, DIM, SEQ);
}

// Round 2
// 459.374 us; speedup vs baseline: 1.3759x; 1.1656x over previous
//
#include <hip/hip_runtime.h>
#include <stdint.h>

#define SEQ 4096
#define DIM 1024

typedef __bf16 bf16x8 __attribute__((ext_vector_type(8)));
typedef float f32x4 __attribute__((ext_vector_type(4)));
typedef unsigned short u16;

__device__ __forceinline__ u16 f2bf(float f) {
    unsigned u = __float_as_uint(f);
    u += 0x7fffu + ((u >> 16) & 1u);     // RNE
    return (u16)(u >> 16);
}
__device__ __forceinline__ float bf2f(u16 h) {
    return __uint_as_float(((unsigned)h) << 16);
}

// global(16B) -> LDS direct copy; LDS dest is wave-uniform base + lane*16.
__device__ __forceinline__ void gload16(const u16* g, u16* l) {
    __builtin_amdgcn_global_load_lds(
        (const __attribute__((address_space(1))) void*)g,
        (__attribute__((address_space(3))) void*)l, 16, 0, 0);
}

// ---------------------------------------------------------------------------
// Kernel 1: h = rmsnorm(emb[x]) * norm_w, written directly as bf16 hi/lo pair
// ---------------------------------------------------------------------------
__global__ __launch_bounds__(256) void embed_rmsnorm_split(
    const int* __restrict__ x, const float* __restrict__ emb,
    const float* __restrict__ nw, u16* __restrict__ hh, u16* __restrict__ hl)
{
    const int row  = blockIdx.x;
    const int t    = threadIdx.x;
    const int lane = t & 63, wave = t >> 6;

    bool i64 = true;
    #pragma unroll
    for (int i = 1; i < 128; i += 2) i64 = i64 && (x[i] == 0);
    const int id = i64 ? x[2 * row] : x[row];

    float4 e = *(const float4*)(emb + (size_t)id * DIM + t * 4);
    float ss = e.x*e.x + e.y*e.y + e.z*e.z + e.w*e.w;
    #pragma unroll
    for (int off = 32; off > 0; off >>= 1) ss += __shfl_down(ss, off);

    __shared__ float red[4];
    if (lane == 0) red[wave] = ss;
    __syncthreads();
    float sum = red[0] + red[1] + red[2] + red[3];
    float scale = rsqrtf(sum * (1.0f / DIM) + 1.1920929e-7f);  // fp32 eps

    float4 n = *(const float4*)(nw + t * 4);
    float o0 = e.x * scale * n.x;
    float o1 = e.y * scale * n.y;
    float o2 = e.z * scale * n.z;
    float o3 = e.w * scale * n.w;
    ushort4 oh, ol;
    u16 b;
    b = f2bf(o0); oh.x = b; ol.x = f2bf(o0 - bf2f(b));
    b = f2bf(o1); oh.y = b; ol.y = f2bf(o1 - bf2f(b));
    b = f2bf(o2); oh.z = b; ol.z = f2bf(o2 - bf2f(b));
    b = f2bf(o3); oh.w = b; ol.w = f2bf(o3 - bf2f(b));
    *(ushort4*)(hh + (size_t)row * DIM + t * 4) = oh;
    *(ushort4*)(hl + (size_t)row * DIM + t * 4) = ol;
}

// ---------------------------------------------------------------------------
// Kernel 1b: split Wq/Wk/Wv fp32 -> bf16 hi/lo, stacked [3072, 1024]
// ---------------------------------------------------------------------------
__global__ __launch_bounds__(256) void split_w(
    const float* __restrict__ W0, const float* __restrict__ W1,
    const float* __restrict__ W2, u16* __restrict__ H, u16* __restrict__ L)
{
    const float* W = (blockIdx.y == 0) ? W0 : (blockIdx.y == 1) ? W1 : W2;
    const size_t base = (size_t)blockIdx.y * DIM * DIM;
    const int i = (blockIdx.x * 256 + threadIdx.x) * 4;
    float4 w = *(const float4*)(W + i);
    ushort4 h, l;
    u16 b;
    b = f2bf(w.x); h.x = b; l.x = f2bf(w.x - bf2f(b));
    b = f2bf(w.y); h.y = b; l.y = f2bf(w.y - bf2f(b));
    b = f2bf(w.z); h.z = b; l.z = f2bf(w.z - bf2f(b));
    b = f2bf(w.w); h.w = b; l.w = f2bf(w.w - bf2f(b));
    *(ushort4*)(H + base + i) = h;
    *(ushort4*)(L + base + i) = l;
}

// ---------------------------------------------------------------------------
// Kernel 2: FUSED QKV split-precision GEMM.
// C[4096,3072] = (hh+hl)[4096,1024] * (Wh+Wl)[3072,1024]^T, 3-pass
// (AhBh+AhBl+AlBh), 128x128 tile, BK=32, gload_lds staging.
// Grid (24,32)=768 blocks -> 2-3 blocks/CU (vs 1/CU for the 3 separate
// N=1024 GEMMs: that 1-block/CU exposure was ~320us of the R1 total).
// Epilogue routes by N-region: q -> qhl=[qh|ql], k -> khl=[kh|kl],
// v -> vT bf16 transposed.
// ---------------------------------------------------------------------------
__global__ __launch_bounds__(256, 3) void gemm_qkv(
    const u16* __restrict__ Ah, const u16* __restrict__ Al,
    const u16* __restrict__ Bh, const u16* __restrict__ Bl,
    u16* __restrict__ qhl, u16* __restrict__ khl, u16* __restrict__ vT)
{
    __shared__ __align__(16) u16 Ash[128 * 32];
    __shared__ __align__(16) u16 Asl[128 * 32];
    __shared__ __align__(16) u16 Bsh[128 * 32];
    __shared__ __align__(16) u16 Bsl[128 * 32];

    const int tid  = threadIdx.x;
    const int lane = tid & 63;
    const int wave = tid >> 6;
    const int m0   = blockIdx.y * 128;
    const int n0   = blockIdx.x * 128;
    const int wr   = (wave >> 1) * 64;
    const int wc   = (wave & 1) * 64;
    const int half = lane >> 4;
    const int l16  = lane & 15;

    f32x4 acc[4][4] = {};

    const int arow = tid >> 2;
    const int acol = (tid & 3) * 8;
    const int wb   = wave * 512;

    for (int k0 = 0; k0 < DIM; k0 += 32) {
        __syncthreads();
        const size_t aoff = (size_t)(m0 + arow) * DIM + k0 + acol;
        const size_t boff = (size_t)(n0 + arow) * DIM + k0 + acol;
        gload16(Ah + aoff,            &Ash[wb]);
        gload16(Ah + aoff + 64 * DIM, &Ash[2048 + wb]);
        gload16(Al + aoff,            &Asl[wb]);
        gload16(Al + aoff + 64 * DIM, &Asl[2048 + wb]);
        gload16(Bh + boff,            &Bsh[wb]);
        gload16(Bh + boff + 64 * DIM, &Bsh[2048 + wb]);
        gload16(Bl + boff,            &Bsl[wb]);
        gload16(Bl + boff + 64 * DIM, &Bsl[2048 + wb]);
        __syncthreads();

        bf16x8 afh[4], afl[4], bfh[4], bfl[4];
        #pragma unroll
        for (int i = 0; i < 4; ++i) {
            afh[i] = *(const bf16x8*)&Ash[(wr + i*16 + l16) * 32 + half * 8];
            afl[i] = *(const bf16x8*)&Asl[(wr + i*16 + l16) * 32 + half * 8];
        }
        #pragma unroll
        for (int j = 0; j < 4; ++j) {
            bfh[j] = *(const bf16x8*)&Bsh[(wc + j*16 + l16) * 32 + half * 8];
            bfl[j] = *(const bf16x8*)&Bsl[(wc + j*16 + l16) * 32 + half * 8];
        }
        #pragma unroll
        for (int i = 0; i < 4; ++i)
            #pragma unroll
            for (int j = 0; j < 4; ++j) {
                acc[i][j] = __builtin_amdgcn_mfma_f32_16x16x32_bf16(afh[i], bfh[j], acc[i][j], 0, 0, 0);
                acc[i][j] = __builtin_amdgcn_mfma_f32_16x16x32_bf16(afh[i], bfl[j], acc[i][j], 0, 0, 0);
                acc[i][j] = __builtin_amdgcn_mfma_f32_16x16x32_bf16(afl[i], bfh[j], acc[i][j], 0, 0, 0);
            }
    }

    const int reg = n0 >> 10;   // 0=q, 1=k, 2=v (block-uniform, 128-wide tile)
    #pragma unroll
    for (int i = 0; i < 4; ++i)
        #pragma unroll
        for (int j = 0; j < 4; ++j)
            #pragma unroll
            for (int r = 0; r < 4; ++r) {
                int row = m0 + wr + i * 16 + half * 4 + r;
                int col = n0 + wc + j * 16 + l16;
                float val = acc[i][j][r];
                u16 hi = f2bf(val);
                if (reg == 0) {
                    qhl[(size_t)row * 2048 + col]        = hi;
                    qhl[(size_t)row * 2048 + col + 1024] = f2bf(val - bf2f(hi));
                } else if (reg == 1) {
                    int c = col - 1024;
                    khl[(size_t)row * 2048 + c]          = hi;
                    khl[(size_t)row * 2048 + c + 1024]   = f2bf(val - bf2f(hi));
                } else {
                    vT[(size_t)(col - 2048) * SEQ + row] = hi;
                }
            }
}

// ---------------------------------------------------------------------------
// Kernel 3: Sc = q.k^T as single-pass bf16 GEMM with VIRTUAL K'=3072.
// A3 = [qh|ql|qh] (cols of qhl with k'>=2048 wrapping to qh),
// B3 = [kh|kh|kl] (cols of khl with k'>=1024 shifted by -1024).
// Segment sum = qh.kh + ql.kh + qh.kl == the 3-pass split product.
// 16 KB LDS, BK=32, grid (32,32).
// ---------------------------------------------------------------------------
__global__ __launch_bounds__(256, 3) void gemm_sc(
    const u16* __restrict__ Q, const u16* __restrict__ Kk,
    float* __restrict__ C)
{
    __shared__ __align__(16) u16 As[128 * 32];
    __shared__ __align__(16) u16 Bs[128 * 32];

    const int tid  = threadIdx.x;
    const int lane = tid & 63;
    const int wave = tid >> 6;
    const int m0   = blockIdx.y * 128;
    const int n0   = blockIdx.x * 128;
    const int wr   = (wave >> 1) * 64;
    const int wc   = (wave & 1) * 64;
    const int half = lane >> 4;
    const int l16  = lane & 15;

    f32x4 acc[4][4] = {};
    const int arow = tid >> 2;
    const int acol = (tid & 3) * 8;
    const int wb   = wave * 512;

    for (int k0 = 0; k0 < 3072; k0 += 32) {
        const int ka = (k0 < 2048) ? k0 : k0 - 2048;   // seg2 re-reads qh
        const int kb = (k0 < 1024) ? k0 : k0 - 1024;   // seg1 re-reads kh, seg2 = kl
        __syncthreads();
        gload16(Q  + (size_t)(m0 + arow)      * 2048 + ka + acol, &As[wb]);
        gload16(Q  + (size_t)(m0 + 64 + arow) * 2048 + ka + acol, &As[2048 + wb]);
        gload16(Kk + (size_t)(n0 + arow)      * 2048 + kb + acol, &Bs[wb]);
        gload16(Kk + (size_t)(n0 + 64 + arow) * 2048 + kb + acol, &Bs[2048 + wb]);
        __syncthreads();

        bf16x8 af[4], bfr[4];
        #pragma unroll
        for (int i = 0; i < 4; ++i)
            af[i] = *(const bf16x8*)&As[(wr + i*16 + l16) * 32 + half * 8];
        #pragma unroll
        for (int j = 0; j < 4; ++j)
            bfr[j] = *(const bf16x8*)&Bs[(wc + j*16 + l16) * 32 + half * 8];
        #pragma unroll
        for (int i = 0; i < 4; ++i)
            #pragma unroll
            for (int j = 0; j < 4; ++j)
                acc[i][j] = __builtin_amdgcn_mfma_f32_16x16x32_bf16(af[i], bfr[j], acc[i][j], 0, 0, 0);
    }

    #pragma unroll
    for (int i = 0; i < 4; ++i)
        #pragma unroll
        for (int j = 0; j < 4; ++j)
            #pragma unroll
            for (int r = 0; r < 4; ++r) {
                int row = m0 + wr + i * 16 + half * 4 + r;
                int col = n0 + wc + j * 16 + l16;
                C[(size_t)row * SEQ + col] = acc[i][j][r];
            }
}

// ---------------------------------------------------------------------------
// Kernel 4: row softmax over fp32 [SEQ, SEQ]; writes bf16 P packed in-place
// into each row's own fp32 footprint (element pitch 2*SEQ u16 per row).
// ---------------------------------------------------------------------------
__global__ __launch_bounds__(256) void softmax_rows(float* __restrict__ S)
{
    const int row  = blockIdx.x;
    const int t    = threadIdx.x;
    const int lane = t & 63, wave = t >> 6;
    float* rp = S + (size_t)row * SEQ;

    float v[16];
    #pragma unroll
    for (int i = 0; i < 4; ++i) {
        float4 f = *(const float4*)(rp + i * 1024 + t * 4);
        v[i*4+0] = f.x; v[i*4+1] = f.y; v[i*4+2] = f.z; v[i*4+3] = f.w;
    }

    float m = v[0];
    #pragma unroll
    for (int i = 1; i < 16; ++i) m = fmaxf(m, v[i]);
    #pragma unroll
    for (int off = 32; off > 0; off >>= 1) m = fmaxf(m, __shfl_down(m, off));
    __shared__ float red[4];
    if (lane == 0) red[wave] = m;
    __syncthreads();
    m = fmaxf(fmaxf(red[0], red[1]), fmaxf(red[2], red[3]));
    __syncthreads();

    float s = 0.0f;
    #pragma unroll
    for (int i = 0; i < 16; ++i) { v[i] = __expf(v[i] - m); s += v[i]; }
    #pragma unroll
    for (int off = 32; off > 0; off >>= 1) s += __shfl_down(s, off);
    if (lane == 0) red[wave] = s;
    __syncthreads();
    s = red[0] + red[1] + red[2] + red[3];
    float inv = 1.0f / s;

    u16* op = (u16*)rp;
    #pragma unroll
    for (int i = 0; i < 4; ++i) {
        ushort4 o;
        o.x = f2bf(v[i*4+0] * inv);
        o.y = f2bf(v[i*4+1] * inv);
        o.z = f2bf(v[i*4+2] * inv);
        o.w = f2bf(v[i*4+3] * inv);
        *(ushort4*)(op + i * 1024 + t * 4) = o;
    }
}

// ---------------------------------------------------------------------------
// Kernel 5: PV GEMM, split-K=2 (512 blocks -> 2/CU, vs 256 -> 1/CU).
// A: bf16 P, element pitch 8192; B: vT [1024, 4096]. fp32 partial out.
// ---------------------------------------------------------------------------
__global__ __launch_bounds__(256, 3) void gemm_pv_partial(
    const u16* __restrict__ A, const u16* __restrict__ B,
    float* __restrict__ P0, float* __restrict__ P1)
{
    __shared__ __align__(16) u16 As[128 * 32];
    __shared__ __align__(16) u16 Bs[128 * 32];

    const int tid  = threadIdx.x;
    const int lane = tid & 63;
    const int wave = tid >> 6;
    const int m0   = blockIdx.y * 128;
    const int n0   = blockIdx.x * 128;
    const int wr   = (wave >> 1) * 64;
    const int wc   = (wave & 1) * 64;
    const int half = lane >> 4;
    const int l16  = lane & 15;

    float* C = blockIdx.z ? P1 : P0;
    const int kbase = blockIdx.z * 2048;

    f32x4 acc[4][4] = {};
    const int arow = tid >> 2;
    const int acol = (tid & 3) * 8;
    const int wb   = wave * 512;

    for (int k0 = kbase; k0 < kbase + 2048; k0 += 32) {
        __syncthreads();
        gload16(A + (size_t)(m0 + arow)      * 8192 + k0 + acol, &As[wb]);
        gload16(A + (size_t)(m0 + 64 + arow) * 8192 + k0 + acol, &As[2048 + wb]);
        gload16(B + (size_t)(n0 + arow)      * 4096 + k0 + acol, &Bs[wb]);
        gload16(B + (size_t)(n0 + 64 + arow) * 4096 + k0 + acol, &Bs[2048 + wb]);
        __syncthreads();

        bf16x8 af[4], bfr[4];
        #pragma unroll
        for (int i = 0; i < 4; ++i)
            af[i] = *(const bf16x8*)&As[(wr + i*16 + l16) * 32 + half * 8];
        #pragma unroll
        for (int j = 0; j < 4; ++j)
            bfr[j] = *(const bf16x8*)&Bs[(wc + j*16 + l16) * 32 + half * 8];
        #pragma unroll
        for (int i = 0; i < 4; ++i)
            #pragma unroll
            for (int j = 0; j < 4; ++j)
                acc[i][j] = __builtin_amdgcn_mfma_f32_16x16x32_bf16(af[i], bfr[j], acc[i][j], 0, 0, 0);
    }

    #pragma unroll
    for (int i = 0; i < 4; ++i)
        #pragma unroll
        for (int j = 0; j < 4; ++j)
            #pragma unroll
            for (int r = 0; r < 4; ++r) {
                int row = m0 + wr + i * 16 + half * 4 + r;
                int col = n0 + wc + j * 16 + l16;
                C[(size_t)row * DIM + col] = acc[i][j][r];
            }
}

// ---------------------------------------------------------------------------
// Kernel 6: out = silu(P0 + P1)
// ---------------------------------------------------------------------------
__global__ __launch_bounds__(256) void combine_silu(
    const float* __restrict__ P0, const float* __restrict__ P1,
    float* __restrict__ out)
{
    const int i = (blockIdx.x * 256 + threadIdx.x) * 4;
    float4 a = *(const float4*)(P0 + i);
    float4 b = *(const float4*)(P1 + i);
    float4 o;
    float v;
    v = a.x + b.x; o.x = v / (1.0f + __expf(-v));
    v = a.y + b.y; o.y = v / (1.0f + __expf(-v));
    v = a.z + b.z; o.z = v / (1.0f + __expf(-v));
    v = a.w + b.w; o.w = v / (1.0f + __expf(-v));
    *(float4*)(out + i) = o;
}

// ---------------------------------------------------------------------------
extern "C" void kernel_launch(void* const* d_in, const int* in_sizes, int n_in,
                              void* d_out, int out_size, void* d_ws, size_t ws_size,
                              hipStream_t stream)
{
    // x int32; emb/norm_w/Wq/Wk/Wv fp32; OUTPUT fp32 (R7-proven contract)
    const int*   x   = (const int*)d_in[0];
    const float* emb = (const float*)d_in[1];
    const float* nw  = (const float*)d_in[2];
    const float* Wq  = (const float*)d_in[3];
    const float* Wk  = (const float*)d_in[4];
    const float* Wv  = (const float*)d_in[5];
    float* out = (float*)d_out;

    // ws layout (104 MB total, R7-proven size):
    //   [  0,  8) vT   bf16 [DIM,SEQ]           (QKV -> PV)
    //   [  8, 24) qhl  bf16 [SEQ,2048]=[qh|ql]  (QKV -> Sc)
    //   [ 24, 40) khl  bf16 [SEQ,2048]=[kh|kl]  (QKV -> Sc)
    //   [ 40,104) Sc   fp32 [SEQ,SEQ]           (Sc -> softmax -> PV)
    //   hh[40,48) hl[48,56) Wh[56,62) Wl[62,68) overlap Sc head; dead
    //     before the Sc GEMM writes (stream-ordered).
    //   P0[8,24) P1[24,40) overlap q/k; q/k dead before PV writes.
    char* ws = (char*)d_ws;
    u16*   vT  = (u16*)(ws);
    u16*   qhl = (u16*)(ws + ( 8u << 20));
    u16*   khl = (u16*)(ws + (24u << 20));
    float* Sc  = (float*)(ws + (40u << 20));
    u16*   hh  = (u16*)(ws + (40u << 20));
    u16*   hl  = (u16*)(ws + (48u << 20));
    u16*   Wh  = (u16*)(ws + (56u << 20));   // [3072,1024] stacked q,k,v
    u16*   Wl  = (u16*)(ws + (62u << 20));
    float* P0  = (float*)(ws + ( 8u << 20));
    float* P1  = (float*)(ws + (24u << 20));

    embed_rmsnorm_split<<<SEQ, 256, 0, stream>>>(x, emb, nw, hh, hl);
    split_w<<<dim3(DIM * DIM / 1024, 3), 256, 0, stream>>>(Wq, Wk, Wv, Wh, Wl);

    // fused QKV: C[4096,3072] = h * [Wq;Wk;Wv]^T, 768 blocks
    gemm_qkv<<<dim3(3072 / 128, SEQ / 128), 256, 0, stream>>>(
        hh, hl, Wh, Wl, qhl, khl, vT);

    // Sc = q.k^T, virtual K'=3072 single-pass bf16
    gemm_sc<<<dim3(SEQ / 128, SEQ / 128), 256, 0, stream>>>(qhl, khl, Sc);

    softmax_rows<<<SEQ, 256, 0, stream>>>(Sc);

    // PV split-K=2: P (bf16, pitch 8192) x vT -> P0/P1 fp32
    gemm_pv_partial<<<dim3(DIM / 128, SEQ / 128, 2), 256, 0, stream>>>(
        (const u16*)Sc, vT, P0, P1);

    combine_silu<<<SEQ * DIM / 1024, 256, 0, stream>>>(P0, P1, out);
}

// Round 3
// 444.885 us; speedup vs baseline: 1.4207x; 1.0326x over previous
//
#include <hip/hip_runtime.h>
#include <stdint.h>

#define SEQ 4096
#define DIM 1024

typedef __bf16 bf16x8 __attribute__((ext_vector_type(8)));
typedef float f32x4 __attribute__((ext_vector_type(4)));
typedef unsigned short u16;

__device__ __forceinline__ u16 f2bf(float f) {
    unsigned u = __float_as_uint(f);
    u += 0x7fffu + ((u >> 16) & 1u);     // RNE
    return (u16)(u >> 16);
}
__device__ __forceinline__ float bf2f(u16 h) {
    return __uint_as_float(((unsigned)h) << 16);
}

// global(16B) -> LDS direct copy; LDS dest is wave-uniform base + lane*16.
__device__ __forceinline__ void gload16(const u16* g, u16* l) {
    __builtin_amdgcn_global_load_lds(
        (const __attribute__((address_space(1))) void*)g,
        (__attribute__((address_space(3))) void*)l, 16, 0, 0);
}

// ---------------------------------------------------------------------------
// Kernel 1: h = rmsnorm(emb[x]) * norm_w, written directly as bf16 hi/lo pair
// ---------------------------------------------------------------------------
__global__ __launch_bounds__(256) void embed_rmsnorm_split(
    const int* __restrict__ x, const float* __restrict__ emb,
    const float* __restrict__ nw, u16* __restrict__ hh, u16* __restrict__ hl)
{
    const int row  = blockIdx.x;
    const int t    = threadIdx.x;
    const int lane = t & 63, wave = t >> 6;

    bool i64 = true;
    #pragma unroll
    for (int i = 1; i < 128; i += 2) i64 = i64 && (x[i] == 0);
    const int id = i64 ? x[2 * row] : x[row];

    float4 e = *(const float4*)(emb + (size_t)id * DIM + t * 4);
    float ss = e.x*e.x + e.y*e.y + e.z*e.z + e.w*e.w;
    #pragma unroll
    for (int off = 32; off > 0; off >>= 1) ss += __shfl_down(ss, off);

    __shared__ float red[4];
    if (lane == 0) red[wave] = ss;
    __syncthreads();
    float sum = red[0] + red[1] + red[2] + red[3];
    float scale = rsqrtf(sum * (1.0f / DIM) + 1.1920929e-7f);  // fp32 eps

    float4 n = *(const float4*)(nw + t * 4);
    float o0 = e.x * scale * n.x;
    float o1 = e.y * scale * n.y;
    float o2 = e.z * scale * n.z;
    float o3 = e.w * scale * n.w;
    ushort4 oh, ol;
    u16 b;
    b = f2bf(o0); oh.x = b; ol.x = f2bf(o0 - bf2f(b));
    b = f2bf(o1); oh.y = b; ol.y = f2bf(o1 - bf2f(b));
    b = f2bf(o2); oh.z = b; ol.z = f2bf(o2 - bf2f(b));
    b = f2bf(o3); oh.w = b; ol.w = f2bf(o3 - bf2f(b));
    *(ushort4*)(hh + (size_t)row * DIM + t * 4) = oh;
    *(ushort4*)(hl + (size_t)row * DIM + t * 4) = ol;
}

// ---------------------------------------------------------------------------
// Kernel 1b: split Wq/Wk/Wv fp32 -> bf16 hi/lo, stacked [3072, 1024]
// ---------------------------------------------------------------------------
__global__ __launch_bounds__(256) void split_w(
    const float* __restrict__ W0, const float* __restrict__ W1,
    const float* __restrict__ W2, u16* __restrict__ H, u16* __restrict__ L)
{
    const float* W = (blockIdx.y == 0) ? W0 : (blockIdx.y == 1) ? W1 : W2;
    const size_t base = (size_t)blockIdx.y * DIM * DIM;
    const int i = (blockIdx.x * 256 + threadIdx.x) * 4;
    float4 w = *(const float4*)(W + i);
    ushort4 h, l;
    u16 b;
    b = f2bf(w.x); h.x = b; l.x = f2bf(w.x - bf2f(b));
    b = f2bf(w.y); h.y = b; l.y = f2bf(w.y - bf2f(b));
    b = f2bf(w.z); h.z = b; l.z = f2bf(w.z - bf2f(b));
    b = f2bf(w.w); h.w = b; l.w = f2bf(w.w - bf2f(b));
    *(ushort4*)(H + base + i) = h;
    *(ushort4*)(L + base + i) = l;
}

// ---------------------------------------------------------------------------
// Kernel 2: FUSED QKV split-precision GEMM (unchanged from R2).
// ---------------------------------------------------------------------------
__global__ __launch_bounds__(256, 3) void gemm_qkv(
    const u16* __restrict__ Ah, const u16* __restrict__ Al,
    const u16* __restrict__ Bh, const u16* __restrict__ Bl,
    u16* __restrict__ qhl, u16* __restrict__ khl, u16* __restrict__ vT)
{
    __shared__ __align__(16) u16 Ash[128 * 32];
    __shared__ __align__(16) u16 Asl[128 * 32];
    __shared__ __align__(16) u16 Bsh[128 * 32];
    __shared__ __align__(16) u16 Bsl[128 * 32];

    const int tid  = threadIdx.x;
    const int lane = tid & 63;
    const int wave = tid >> 6;
    const int m0   = blockIdx.y * 128;
    const int n0   = blockIdx.x * 128;
    const int wr   = (wave >> 1) * 64;
    const int wc   = (wave & 1) * 64;
    const int half = lane >> 4;
    const int l16  = lane & 15;

    f32x4 acc[4][4] = {};

    const int arow = tid >> 2;
    const int acol = (tid & 3) * 8;
    const int wb   = wave * 512;

    for (int k0 = 0; k0 < DIM; k0 += 32) {
        __syncthreads();
        const size_t aoff = (size_t)(m0 + arow) * DIM + k0 + acol;
        const size_t boff = (size_t)(n0 + arow) * DIM + k0 + acol;
        gload16(Ah + aoff,            &Ash[wb]);
        gload16(Ah + aoff + 64 * DIM, &Ash[2048 + wb]);
        gload16(Al + aoff,            &Asl[wb]);
        gload16(Al + aoff + 64 * DIM, &Asl[2048 + wb]);
        gload16(Bh + boff,            &Bsh[wb]);
        gload16(Bh + boff + 64 * DIM, &Bsh[2048 + wb]);
        gload16(Bl + boff,            &Bsl[wb]);
        gload16(Bl + boff + 64 * DIM, &Bsl[2048 + wb]);
        __syncthreads();

        bf16x8 afh[4], afl[4], bfh[4], bfl[4];
        #pragma unroll
        for (int i = 0; i < 4; ++i) {
            afh[i] = *(const bf16x8*)&Ash[(wr + i*16 + l16) * 32 + half * 8];
            afl[i] = *(const bf16x8*)&Asl[(wr + i*16 + l16) * 32 + half * 8];
        }
        #pragma unroll
        for (int j = 0; j < 4; ++j) {
            bfh[j] = *(const bf16x8*)&Bsh[(wc + j*16 + l16) * 32 + half * 8];
            bfl[j] = *(const bf16x8*)&Bsl[(wc + j*16 + l16) * 32 + half * 8];
        }
        #pragma unroll
        for (int i = 0; i < 4; ++i)
            #pragma unroll
            for (int j = 0; j < 4; ++j) {
                acc[i][j] = __builtin_amdgcn_mfma_f32_16x16x32_bf16(afh[i], bfh[j], acc[i][j], 0, 0, 0);
                acc[i][j] = __builtin_amdgcn_mfma_f32_16x16x32_bf16(afh[i], bfl[j], acc[i][j], 0, 0, 0);
                acc[i][j] = __builtin_amdgcn_mfma_f32_16x16x32_bf16(afl[i], bfh[j], acc[i][j], 0, 0, 0);
            }
    }

    const int reg = n0 >> 10;   // 0=q, 1=k, 2=v (block-uniform, 128-wide tile)
    #pragma unroll
    for (int i = 0; i < 4; ++i)
        #pragma unroll
        for (int j = 0; j < 4; ++j)
            #pragma unroll
            for (int r = 0; r < 4; ++r) {
                int row = m0 + wr + i * 16 + half * 4 + r;
                int col = n0 + wc + j * 16 + l16;
                float val = acc[i][j][r];
                u16 hi = f2bf(val);
                if (reg == 0) {
                    qhl[(size_t)row * 2048 + col]        = hi;
                    qhl[(size_t)row * 2048 + col + 1024] = f2bf(val - bf2f(hi));
                } else if (reg == 1) {
                    int c = col - 1024;
                    khl[(size_t)row * 2048 + c]          = hi;
                    khl[(size_t)row * 2048 + c + 1024]   = f2bf(val - bf2f(hi));
                } else {
                    vT[(size_t)(col - 2048) * SEQ + row] = hi;
                }
            }
}

// ---------------------------------------------------------------------------
// Kernel 3: Sc = q.k^T, virtual K'=3072, **256x256 8-phase template**
// (T2 st_16x32 swizzle + T3/T4 counted vmcnt + T5 setprio).
// 8 waves (2M x 4N), BK=64, 128 KiB LDS double-buffer, 1 block/CU.
// Stage unit = 64 rows (1 gload16/thread, 512 thr covers 64x64 bf16).
// Stage schedule per K-tile t (staging tile t+2 into the SAME buffer b=t&1):
//   p1: A-Q0,A-Q2  (their tile-t reads retire at p0 barrier)
//   p2: B-Q0..Q3   (B reads retire at p1 barrier)
//   p3: A-Q1,A-Q3  (their reads retire at p2 barrier)
// vmcnt(8) once per K-tile (8 gloads of next tile allowed in flight);
// vmcnt(0) only for the last two tiles. Swizzle: source-permute
// t' = t ^ ((t>>5&1)<<1)  <->  read idx ^= ((row>>2)&1)<<4 (involution).
// ---------------------------------------------------------------------------
#define SC_NT 48
__global__ __launch_bounds__(512, 2) void gemm_sc_8ph(
    const u16* __restrict__ Q, const u16* __restrict__ Kk,
    float* __restrict__ C)
{
    __shared__ __align__(16) u16 Alds[2][256 * 64];
    __shared__ __align__(16) u16 Blds[2][256 * 64];

    const int tid  = threadIdx.x;
    const int lane = tid & 63;
    const int wid  = tid >> 6;
    const int wm   = wid >> 2;      // 0..1
    const int wn   = wid & 3;       // 0..3
    const int l16  = lane & 15;
    const int half = lane >> 4;     // 0..3

    // XCD-aware bijective swizzle (nwg=256, 256%8==0)
    const int wg  = blockIdx.y * 16 + blockIdx.x;
    const int swz = (wg & 7) * 32 + (wg >> 3);
    const int m0  = (swz >> 4) * 256;
    const int n0  = (swz & 15) * 256;

    // staging addresses (pre-swizzled global source, linear LDS dest)
    const int tp   = tid ^ (((tid >> 5) & 1) << 1);
    const int srow = tp >> 3;          // 0..63 within unit
    const int scol = (tp & 7) * 8;
    const u16* paq[4];
    const u16* pbq[4];
    #pragma unroll
    for (int q = 0; q < 4; ++q) {
        paq[q] = Q  + (size_t)(m0 + q * 64 + srow) * 2048 + scol;
        pbq[q] = Kk + (size_t)(n0 + q * 64 + srow) * 2048 + scol;
    }

    // ds_read bases (swizzled read: col ^= ((row>>2)&1)<<4; row bit2 = l16 bit2)
    const int s2    = (l16 >> 2) & 1;
    const int hc    = (half * 8) ^ (s2 << 4);
    const int abase = (wm * 128 + l16) * 64 + hc;   // + i*1024 + ks*32 (+4096 quad1)
    const int bbase = (wn * 64 + l16) * 64 + hc;    // + g*1024 + ks*32 (+2048 pair1)

    // -------- prologue: stage tile0 -> buf0 (k=0), tile1 -> buf1 (k=64)
    {
        u16* a0d = &Alds[0][wid * 512];
        u16* b0d = &Blds[0][wid * 512];
        u16* a1d = &Alds[1][wid * 512];
        u16* b1d = &Blds[1][wid * 512];
        #pragma unroll
        for (int q = 0; q < 4; ++q) gload16(paq[q],      a0d + q * 4096);
        #pragma unroll
        for (int q = 0; q < 4; ++q) gload16(pbq[q],      b0d + q * 4096);
        #pragma unroll
        for (int q = 0; q < 4; ++q) gload16(paq[q] + 64, a1d + q * 4096);
        #pragma unroll
        for (int q = 0; q < 4; ++q) gload16(pbq[q] + 64, b1d + q * 4096);
    }
    asm volatile("s_waitcnt vmcnt(8)" ::: "memory");
    __builtin_amdgcn_sched_barrier(0);
    __builtin_amdgcn_s_barrier();

    f32x4 acc[8][4] = {};
    bf16x8 a0[4][2], b0[2][2], b1[2][2];

    #pragma unroll 1
    for (int t = 0; t < SC_NT; ++t) {
        const int  b        = t & 1;
        const bool do_stage = (t + 2) < SC_NT;
        const int  k2  = (t + 2) * 64;
        const int  ka2 = (k2 < 2048) ? k2 : k2 - 2048;  // qh|ql|qh
        const int  kb2 = (k2 < 1024) ? k2 : k2 - 1024;  // kh|kh|kl
        u16* ald = &Alds[b][wid * 512];
        u16* bld = &Blds[b][wid * 512];

        // ---- phase 0: read A-quad0 (8) + B-pair0 (4); MFMA (Ma, N0)
        #pragma unroll
        for (int i = 0; i < 4; ++i)
            #pragma unroll
            for (int ks = 0; ks < 2; ++ks)
                a0[i][ks] = *(const bf16x8*)&Alds[b][abase + i * 1024 + ks * 32];
        #pragma unroll
        for (int g = 0; g < 2; ++g)
            #pragma unroll
            for (int ks = 0; ks < 2; ++ks)
                b0[g][ks] = *(const bf16x8*)&Blds[b][bbase + g * 1024 + ks * 32];
        __builtin_amdgcn_s_barrier();
        asm volatile("s_waitcnt lgkmcnt(0)" ::: "memory");
        __builtin_amdgcn_sched_barrier(0);
        __builtin_amdgcn_s_setprio(1);
        #pragma unroll
        for (int i = 0; i < 4; ++i)
            #pragma unroll
            for (int g = 0; g < 2; ++g)
                #pragma unroll
                for (int ks = 0; ks < 2; ++ks)
                    acc[i][g] = __builtin_amdgcn_mfma_f32_16x16x32_bf16(a0[i][ks], b0[g][ks], acc[i][g], 0, 0, 0);
        __builtin_amdgcn_s_setprio(0);
        __builtin_amdgcn_s_barrier();

        // ---- phase 1: read B-pair1 (4); stage A-Q0,A-Q2(t+2); MFMA (Ma, N1)
        #pragma unroll
        for (int g = 0; g < 2; ++g)
            #pragma unroll
            for (int ks = 0; ks < 2; ++ks)
                b1[g][ks] = *(const bf16x8*)&Blds[b][bbase + 2048 + g * 1024 + ks * 32];
        if (do_stage) {
            gload16(paq[0] + ka2, ald);
            gload16(paq[2] + ka2, ald + 2 * 4096);
        }
        __builtin_amdgcn_s_barrier();
        asm volatile("s_waitcnt lgkmcnt(0)" ::: "memory");
        __builtin_amdgcn_sched_barrier(0);
        __builtin_amdgcn_s_setprio(1);
        #pragma unroll
        for (int i = 0; i < 4; ++i)
            #pragma unroll
            for (int g = 0; g < 2; ++g)
                #pragma unroll
                for (int ks = 0; ks < 2; ++ks)
                    acc[i][2 + g] = __builtin_amdgcn_mfma_f32_16x16x32_bf16(a0[i][ks], b1[g][ks], acc[i][2 + g], 0, 0, 0);
        __builtin_amdgcn_s_setprio(0);
        __builtin_amdgcn_s_barrier();

        // ---- phase 2: read A-quad1 (8); stage B-Q0..Q3(t+2); MFMA (Mb, N1)
        #pragma unroll
        for (int i = 0; i < 4; ++i)
            #pragma unroll
            for (int ks = 0; ks < 2; ++ks)
                a0[i][ks] = *(const bf16x8*)&Alds[b][abase + 4096 + i * 1024 + ks * 32];
        if (do_stage) {
            gload16(pbq[0] + kb2, bld);
            gload16(pbq[1] + kb2, bld + 4096);
            gload16(pbq[2] + kb2, bld + 2 * 4096);
            gload16(pbq[3] + kb2, bld + 3 * 4096);
        }
        __builtin_amdgcn_s_barrier();
        asm volatile("s_waitcnt lgkmcnt(0)" ::: "memory");
        __builtin_amdgcn_sched_barrier(0);
        __builtin_amdgcn_s_setprio(1);
        #pragma unroll
        for (int i = 0; i < 4; ++i)
            #pragma unroll
            for (int g = 0; g < 2; ++g)
                #pragma unroll
                for (int ks = 0; ks < 2; ++ks)
                    acc[4 + i][2 + g] = __builtin_amdgcn_mfma_f32_16x16x32_bf16(a0[i][ks], b1[g][ks], acc[4 + i][2 + g], 0, 0, 0);
        __builtin_amdgcn_s_setprio(0);
        __builtin_amdgcn_s_barrier();

        // ---- phase 3: stage A-Q1,A-Q3(t+2); MFMA (Mb, N0); vmcnt; barrier
        if (do_stage) {
            gload16(paq[1] + ka2, ald + 4096);
            gload16(paq[3] + ka2, ald + 3 * 4096);
        }
        __builtin_amdgcn_s_barrier();
        __builtin_amdgcn_s_setprio(1);
        #pragma unroll
        for (int i = 0; i < 4; ++i)
            #pragma unroll
            for (int g = 0; g < 2; ++g)
                #pragma unroll
                for (int ks = 0; ks < 2; ++ks)
                    acc[4 + i][g] = __builtin_amdgcn_mfma_f32_16x16x32_bf16(a0[i][ks], b0[g][ks], acc[4 + i][g], 0, 0, 0);
        __builtin_amdgcn_s_setprio(0);
        if (t < SC_NT - 2) { asm volatile("s_waitcnt vmcnt(8)" ::: "memory"); }
        else               { asm volatile("s_waitcnt vmcnt(0)" ::: "memory"); }
        __builtin_amdgcn_sched_barrier(0);
        __builtin_amdgcn_s_barrier();
    }

    // epilogue: C/D layout col=lane&15, row=(lane>>4)*4+reg
    const int crow0 = m0 + wm * 128 + half * 4;
    const int ccol0 = n0 + wn * 64 + l16;
    #pragma unroll
    for (int mf = 0; mf < 8; ++mf)
        #pragma unroll
        for (int nf = 0; nf < 4; ++nf)
            #pragma unroll
            for (int r = 0; r < 4; ++r)
                C[(size_t)(crow0 + mf * 16 + r) * SEQ + ccol0 + nf * 16] = acc[mf][nf][r];
}

// ---------------------------------------------------------------------------
// Kernel 4: row softmax over fp32 [SEQ, SEQ]; writes bf16 P packed in-place
// ---------------------------------------------------------------------------
__global__ __launch_bounds__(256) void softmax_rows(float* __restrict__ S)
{
    const int row  = blockIdx.x;
    const int t    = threadIdx.x;
    const int lane = t & 63, wave = t >> 6;
    float* rp = S + (size_t)row * SEQ;

    float v[16];
    #pragma unroll
    for (int i = 0; i < 4; ++i) {
        float4 f = *(const float4*)(rp + i * 1024 + t * 4);
        v[i*4+0] = f.x; v[i*4+1] = f.y; v[i*4+2] = f.z; v[i*4+3] = f.w;
    }

    float m = v[0];
    #pragma unroll
    for (int i = 1; i < 16; ++i) m = fmaxf(m, v[i]);
    #pragma unroll
    for (int off = 32; off > 0; off >>= 1) m = fmaxf(m, __shfl_down(m, off));
    __shared__ float red[4];
    if (lane == 0) red[wave] = m;
    __syncthreads();
    m = fmaxf(fmaxf(red[0], red[1]), fmaxf(red[2], red[3]));
    __syncthreads();

    float s = 0.0f;
    #pragma unroll
    for (int i = 0; i < 16; ++i) { v[i] = __expf(v[i] - m); s += v[i]; }
    #pragma unroll
    for (int off = 32; off > 0; off >>= 1) s += __shfl_down(s, off);
    if (lane == 0) red[wave] = s;
    __syncthreads();
    s = red[0] + red[1] + red[2] + red[3];
    float inv = 1.0f / s;

    u16* op = (u16*)rp;
    #pragma unroll
    for (int i = 0; i < 4; ++i) {
        ushort4 o;
        o.x = f2bf(v[i*4+0] * inv);
        o.y = f2bf(v[i*4+1] * inv);
        o.z = f2bf(v[i*4+2] * inv);
        o.w = f2bf(v[i*4+3] * inv);
        *(ushort4*)(op + i * 1024 + t * 4) = o;
    }
}

// ---------------------------------------------------------------------------
// Kernel 5: PV GEMM, split-K=2 (512 blocks -> 2/CU).
// ---------------------------------------------------------------------------
__global__ __launch_bounds__(256, 3) void gemm_pv_partial(
    const u16* __restrict__ A, const u16* __restrict__ B,
    float* __restrict__ P0, float* __restrict__ P1)
{
    __shared__ __align__(16) u16 As[128 * 32];
    __shared__ __align__(16) u16 Bs[128 * 32];

    const int tid  = threadIdx.x;
    const int lane = tid & 63;
    const int wave = tid >> 6;
    const int m0   = blockIdx.y * 128;
    const int n0   = blockIdx.x * 128;
    const int wr   = (wave >> 1) * 64;
    const int wc   = (wave & 1) * 64;
    const int half = lane >> 4;
    const int l16  = lane & 15;

    float* C = blockIdx.z ? P1 : P0;
    const int kbase = blockIdx.z * 2048;

    f32x4 acc[4][4] = {};
    const int arow = tid >> 2;
    const int acol = (tid & 3) * 8;
    const int wb   = wave * 512;

    for (int k0 = kbase; k0 < kbase + 2048; k0 += 32) {
        __syncthreads();
        gload16(A + (size_t)(m0 + arow)      * 8192 + k0 + acol, &As[wb]);
        gload16(A + (size_t)(m0 + 64 + arow) * 8192 + k0 + acol, &As[2048 + wb]);
        gload16(B + (size_t)(n0 + arow)      * 4096 + k0 + acol, &Bs[wb]);
        gload16(B + (size_t)(n0 + 64 + arow) * 4096 + k0 + acol, &Bs[2048 + wb]);
        __syncthreads();

        bf16x8 af[4], bfr[4];
        #pragma unroll
        for (int i = 0; i < 4; ++i)
            af[i] = *(const bf16x8*)&As[(wr + i*16 + l16) * 32 + half * 8];
        #pragma unroll
        for (int j = 0; j < 4; ++j)
            bfr[j] = *(const bf16x8*)&Bs[(wc + j*16 + l16) * 32 + half * 8];
        #pragma unroll
        for (int i = 0; i < 4; ++i)
            #pragma unroll
            for (int j = 0; j < 4; ++j)
                acc[i][j] = __builtin_amdgcn_mfma_f32_16x16x32_bf16(af[i], bfr[j], acc[i][j], 0, 0, 0);
    }

    #pragma unroll
    for (int i = 0; i < 4; ++i)
        #pragma unroll
        for (int j = 0; j < 4; ++j)
            #pragma unroll
            for (int r = 0; r < 4; ++r) {
                int row = m0 + wr + i * 16 + half * 4 + r;
                int col = n0 + wc + j * 16 + l16;
                C[(size_t)row * DIM + col] = acc[i][j][r];
            }
}

// ---------------------------------------------------------------------------
// Kernel 6: out = silu(P0 + P1)
// ---------------------------------------------------------------------------
__global__ __launch_bounds__(256) void combine_silu(
    const float* __restrict__ P0, const float* __restrict__ P1,
    float* __restrict__ out)
{
    const int i = (blockIdx.x * 256 + threadIdx.x) * 4;
    float4 a = *(const float4*)(P0 + i);
    float4 b = *(const float4*)(P1 + i);
    float4 o;
    float v;
    v = a.x + b.x; o.x = v / (1.0f + __expf(-v));
    v = a.y + b.y; o.y = v / (1.0f + __expf(-v));
    v = a.z + b.z; o.z = v / (1.0f + __expf(-v));
    v = a.w + b.w; o.w = v / (1.0f + __expf(-v));
    *(float4*)(out + i) = o;
}

// ---------------------------------------------------------------------------
extern "C" void kernel_launch(void* const* d_in, const int* in_sizes, int n_in,
                              void* d_out, int out_size, void* d_ws, size_t ws_size,
                              hipStream_t stream)
{
    const int*   x   = (const int*)d_in[0];
    const float* emb = (const float*)d_in[1];
    const float* nw  = (const float*)d_in[2];
    const float* Wq  = (const float*)d_in[3];
    const float* Wk  = (const float*)d_in[4];
    const float* Wv  = (const float*)d_in[5];
    float* out = (float*)d_out;

    // ws layout (104 MB total, proven):
    //   [  0,  8) vT   bf16 [DIM,SEQ]           (QKV -> PV)
    //   [  8, 24) qhl  bf16 [SEQ,2048]=[qh|ql]  (QKV -> Sc)
    //   [ 24, 40) khl  bf16 [SEQ,2048]=[kh|kl]  (QKV -> Sc)
    //   [ 40,104) Sc   fp32 [SEQ,SEQ]
    //   hh/hl/Wh/Wl overlap Sc head; dead before Sc GEMM writes.
    //   P0/P1 overlap q/k; q/k dead before PV writes.
    char* ws = (char*)d_ws;
    u16*   vT  = (u16*)(ws);
    u16*   qhl = (u16*)(ws + ( 8u << 20));
    u16*   khl = (u16*)(ws + (24u << 20));
    float* Sc  = (float*)(ws + (40u << 20));
    u16*   hh  = (u16*)(ws + (40u << 20));
    u16*   hl  = (u16*)(ws + (48u << 20));
    u16*   Wh  = (u16*)(ws + (56u << 20));   // [3072,1024] stacked q,k,v
    u16*   Wl  = (u16*)(ws + (62u << 20));
    float* P0  = (float*)(ws + ( 8u << 20));
    float* P1  = (float*)(ws + (24u << 20));

    embed_rmsnorm_split<<<SEQ, 256, 0, stream>>>(x, emb, nw, hh, hl);
    split_w<<<dim3(DIM * DIM / 1024, 3), 256, 0, stream>>>(Wq, Wk, Wv, Wh, Wl);

    gemm_qkv<<<dim3(3072 / 128, SEQ / 128), 256, 0, stream>>>(
        hh, hl, Wh, Wl, qhl, khl, vT);

    // Sc = q.k^T, virtual K'=3072, 256^2 8-phase template
    gemm_sc_8ph<<<dim3(SEQ / 256, SEQ / 256), 512, 0, stream>>>(qhl, khl, Sc);

    softmax_rows<<<SEQ, 256, 0, stream>>>(Sc);

    gemm_pv_partial<<<dim3(DIM / 128, SEQ / 128, 2), 256, 0, stream>>>(
        (const u16*)Sc, vT, P0, P1);

    combine_silu<<<SEQ * DIM / 1024, 256, 0, stream>>>(P0, P1, out);
}